// Round 16
// baseline (1144.513 us; speedup 1.0000x reference)
//
#include <hip/hip_runtime.h>
#include <math.h>

// SwinDecoder on MI355X. Round 23: software-pipeline gemm_mfma's K-loop.
// R22 (1131.3us best): mask fold +11.5us. Remaining dominant inefficiency:
// gemm_mfma's 2-barriers-per-k-step staging exposes L2 latency 6-24x per
// block (fc1 59us vs ~22us overlapped floor). Fix = R11's issue-early/
// wait-late dbuf scheme (proven CORRECT in R11; it failed there only
// because mlp_fused's 75KB LDS -> 1 block/CU). gemm_mfma is 12-20KB:
// dbuf -> 24/32/40KB (NT=4/8/12), caps 6/4/3 blocks/CU, all >= measured
// ~2.5 residency. Barriers/k-step 2->1; loads overlap MFMA.
// Everything else identical to R22.
// ws layout (bytes):
//   e        : 0          .. 50,331,648   fp32 [65536][192]
//   bias_il  : 50,331,648 .. 51,118,080   bf16 interleaved [4][6][16384] (pre-scaled)
//   wt       : 51,904,512 .. 55,541,760   bf16 weights (4 layers + pe + rec)
//   stage    : 55,541,760 .. attn: bufc|qkc|vc|oc ; mlp: a(384B/row)|h(1536B/row)

#define CCH 192
#define HEADS 6

typedef __attribute__((ext_vector_type(8))) short bf16x8;
typedef __attribute__((ext_vector_type(4))) float f32x4;

__device__ __forceinline__ unsigned short f2bf(float f){
    union { float f; unsigned int u; } x; x.f = f;
    unsigned int r = (x.u + 0x7fffu + ((x.u >> 16) & 1u)) >> 16;
    return (unsigned short)r;
}
__device__ __forceinline__ float bf2f(unsigned short h){
    union { unsigned int u; float f; } x; x.u = ((unsigned int)h)<<16;
    return x.f;
}

__device__ __forceinline__ void async16(const void* g, void* l){
    __builtin_amdgcn_global_load_lds(
        (const __attribute__((address_space(1))) void*)g,
        (__attribute__((address_space(3))) void*)l, 16, 0, 0);
}

__device__ __forceinline__ ushort4 cvt4(float4 v){
    ushort4 r; r.x=f2bf(v.x); r.y=f2bf(v.y); r.z=f2bf(v.z); r.w=f2bf(v.w);
    return r;
}

__device__ __forceinline__ int zone_z(int z){ return z<30?0:(z<31?1:2); }
__device__ __forceinline__ int zone_hw(int h){ return h<24?0:(h<28?1:2); }

// gelu with A&S 7.1.26 erf: |err| <= 1.5e-7, branchless, 1 v_exp + 1 v_rcp.
__device__ __forceinline__ float gelu_f(float v){
    float xx = v*0.70710678118654752f;
    float ax = fabsf(xx);
    float ti = __builtin_amdgcn_rcpf(fmaf(0.3275911f, ax, 1.f));
    float p  = fmaf(ti, 1.061405429f, -1.453152027f);
    p = fmaf(ti, p, 1.421413741f);
    p = fmaf(ti, p, -0.284496736f);
    p = fmaf(ti, p, 0.254829592f);
    p = p * ti;
    float ex = __expf(-ax*ax);
    float er = fmaf(-p, ex, 1.f);
    er = __builtin_copysignf(er, xx);
    return 0.5f*v*(1.f + er);
}

// ---------------- weight convert+transpose: w[K][N] fp32 -> wt[N][K] bf16 --
__global__ void wt_convert(const float* __restrict__ w, unsigned short* __restrict__ wt,
                           int K, int N)
{
    int idx = blockIdx.x*256 + threadIdx.x;
    if (idx >= K*N) return;
    int n = idx / K, k = idx - n*K;
    wt[idx] = f2bf(w[(size_t)k*N + n]);
}

// ---------------- plain fp32 -> bf16 convert -------------------------------
__global__ void pe_conv(const float* __restrict__ w, unsigned short* __restrict__ o, int n)
{
    int i = blockIdx.x*256 + threadIdx.x;
    if (i < n) o[i] = f2bf(w[i]);
}

// ---- rel-pos bias -> bf16 in MFMA-interleaved layout, PRE-SCALED by ------
// 1/attn_scale so it can be the MFMA C-initializer (s = acc*scale).
__global__ void bias_precompute(const float* __restrict__ rpb,
                                unsigned short* __restrict__ bias_il)
{
    const float inv_scale = 5.656854249492380f;
    int d = blockIdx.x / HEADS, head = blockIdx.x % HEADS;
    int n = threadIdx.x;
    int i1 = n>>6, j1 = (n>>3)&7, k1 = n&7;
    const float* rp = rpb + d*675*HEADS;
    unsigned short* out = bias_il + (size_t)blockIdx.x*16384;
    int rbase = (n>>4)*2048 + (n&15)*8;
    for (int m = 0; m < 128; ++m){
        int i2 = m>>6, j2 = (m>>3)&7, k2 = m&7;
        int idx = (i1-i2+1)*225 + (j1-j2+7)*15 + (k1-k2+7);
        int off = rbase + (m>>5)*512 + ((m>>3)&3)*128 + (m&7);
        out[off] = f2bf(rp[idx*HEADS + head] * inv_scale);
    }
}

// ---------------- patch embed via MFMA, LN fused in epilogue ---------------
__global__ __launch_bounds__(256) void patch_embed_mfma(
    const float* __restrict__ x, const unsigned short* __restrict__ pwb,
    const float* __restrict__ pe_b, const float* __restrict__ gg,
    const float* __restrict__ bb, float* __restrict__ e)
{
    __shared__ __align__(16) unsigned short As[64*132];
    __shared__ __align__(16) unsigned short Bs[96*132];
    int t = threadIdx.x;
    int wave = t>>6, lane = t&63, quad = lane>>4, l16 = lane&15;
    int m0 = blockIdx.x*64;

    {
        int row = t & 63, cg = (t>>6)*8;
        int pos = m0 + row;
        int w = pos&31, h=(pos>>5)&31, z=(pos>>10)&31, b=pos>>15;
        #pragma unroll
        for (int cc=0; cc<8; ++cc){
            int chunk = cg + cc;
            int c = chunk>>3, i=(chunk>>2)&1, j=chunk&3;
            float4 v = *(const float4*)&x[ (((size_t)(b*4+c)*64 + (z*2+i))*128 + (h*4+j))*128 + w*4 ];
            *(ushort4*)&As[row*132 + chunk*4] = cvt4(v);
        }
    }

    f32x4 acc[12] = {};
    #pragma unroll
    for (int ph = 0; ph < 2; ++ph){
        if (ph) __syncthreads();
        #pragma unroll
        for (int it=0; it<6; ++it){
            int g = it*256 + t;
            int row = g >> 4, c8 = g & 15;
            const unsigned short* src = pwb + ((size_t)(ph*96+row))*128 + c8*8;
            uint4 u = *(const uint4*)src;
            unsigned short* dst = &Bs[row*132 + c8*8];
            *(uint2*)dst       = make_uint2(u.x, u.y);
            *(uint2*)(dst+4)   = make_uint2(u.z, u.w);
        }
        __syncthreads();
        #pragma unroll
        for (int ks=0; ks<4; ++ks){
            bf16x8 af = *(const bf16x8*)&As[(wave*16 + l16)*132 + ks*32 + quad*8];
            #pragma unroll
            for (int nt=0; nt<6; ++nt){
                bf16x8 bf = *(const bf16x8*)&Bs[(nt*16 + l16)*132 + ks*32 + quad*8];
                acc[ph*6+nt] = __builtin_amdgcn_mfma_f32_16x16x32_bf16(
                    af, bf, acc[ph*6+nt], 0, 0, 0);
            }
        }
    }

    float pb[12], gv[12], bv[12];
    #pragma unroll
    for (int nt=0; nt<12; ++nt){
        int col = nt*16 + l16;
        pb[nt] = pe_b[col]; gv[nt] = gg[col]; bv[nt] = bb[col];
    }
    #pragma unroll
    for (int r=0; r<4; ++r){
        int row = wave*16 + quad*4 + r;
        int pos = m0 + row;
        float sv[12], s1 = 0.f, s2 = 0.f;
        #pragma unroll
        for (int nt=0; nt<12; ++nt){
            float v = acc[nt][r] + pb[nt];
            sv[nt] = v; s1 += v; s2 += v*v;
        }
        #pragma unroll
        for (int off=1; off<16; off<<=1){
            s1 += __shfl_xor(s1, off); s2 += __shfl_xor(s2, off);
        }
        float mean = s1*(1.f/192.f);
        float rstd = rsqrtf(s2*(1.f/192.f) - mean*mean + 1e-5f);
        #pragma unroll
        for (int nt=0; nt<12; ++nt){
            int col = nt*16 + l16;
            e[(size_t)pos*CCH + col] = (sv[nt]-mean)*rstd*gv[nt] + bv[nt];
        }
    }
}

// ---------------- reconstruction via MFMA ----------------------------------
__global__ __launch_bounds__(256) void recon_mfma(
    const float* __restrict__ e, const unsigned short* __restrict__ rwt,
    const float* __restrict__ rec_b, float* __restrict__ out)
{
    __shared__ __align__(16) unsigned short As[64*196];
    __shared__ __align__(16) unsigned short Bs[64*196];
    int t = threadIdx.x;
    int wave = t>>6, lane = t&63, quad = lane>>4, l16 = lane&15;
    int m0 = blockIdx.x*64;

    #pragma unroll
    for (int it=0; it<12; ++it){
        int g = it*256 + t;
        int row = g/48, c4 = g - row*48;
        float4 v = *(const float4*)&e[(size_t)(m0+row)*CCH + c4*4];
        *(ushort4*)&As[row*196 + c4*4] = cvt4(v);
    }

    f32x4 acc[8] = {};
    #pragma unroll
    for (int ph = 0; ph < 2; ++ph){
        if (ph) __syncthreads();
        #pragma unroll
        for (int it=0; it<6; ++it){
            int g = it*256 + t;
            int row = g/24, c8 = g - row*24;
            const unsigned short* src = rwt + ((size_t)(ph*64+row))*192 + c8*8;
            uint4 u = *(const uint4*)src;
            unsigned short* dst = &Bs[row*196 + c8*8];
            *(uint2*)dst     = make_uint2(u.x, u.y);
            *(uint2*)(dst+4) = make_uint2(u.z, u.w);
        }
        __syncthreads();
        #pragma unroll
        for (int ks=0; ks<6; ++ks){
            bf16x8 af = *(const bf16x8*)&As[(wave*16 + l16)*196 + ks*32 + quad*8];
            #pragma unroll
            for (int nt=0; nt<4; ++nt){
                bf16x8 bf = *(const bf16x8*)&Bs[(nt*16 + l16)*196 + ks*32 + quad*8];
                acc[ph*4+nt] = __builtin_amdgcn_mfma_f32_16x16x32_bf16(
                    af, bf, acc[ph*4+nt], 0, 0, 0);
            }
        }
    }

    #pragma unroll
    for (int nt=0; nt<8; ++nt){
        int col = nt*16 + l16;
        int o = col>>5, i = (col>>4)&1, j = (col>>2)&3, k = col&3;
        float rb = rec_b[o];
        #pragma unroll
        for (int r=0; r<4; ++r){
            int pos = m0 + wave*16 + quad*4 + r;
            int w = pos&31, h=(pos>>5)&31, z=(pos>>10)&31, b=pos>>15;
            out[ (((size_t)(b*4+o)*64 + (z*2+i))*128 + (h*4+j))*128 + (w*4+k) ]
                = acc[nt][r] + rb;
        }
    }
}

// ------- LayerNorm -> bf16 (wave-per-row, 4 waves x 2 rows/block) ----------
// gather=1: window gather (ln1); 0: plain (ln2). Pure 64-lane butterfly,
// no LDS, no barrier. Grid = rows/8.
__global__ __launch_bounds__(256) void ln_kernel(
    const float* __restrict__ in, unsigned short* __restrict__ outp,
    const float* __restrict__ gg, const float* __restrict__ bb,
    int shifted, int row0, int gather)
{
    int lane = threadIdx.x & 63, wave = threadIdx.x >> 6;
    float g0 = gg[lane],  gA = gg[lane+64],  gB = gg[lane+128];
    float c0 = bb[lane],  cA = bb[lane+64],  cB = bb[lane+128];
    #pragma unroll
    for (int rr = 0; rr < 2; ++rr){
        int lr = blockIdx.x*8 + wave*2 + rr;   // chunk-local row
        int r  = lr + row0;                    // global gathered-row index
        int src;
        if (gather){
            int wb = r>>7, tok = r&127;
            int b = wb>>8, nw = wb&255;
            int zs = (nw>>4)*2 + (tok>>6);
            int hs = ((nw>>2)&3)*8 + ((tok>>3)&7);
            int ws = (nw&3)*8 + (tok&7);
            int z,h,w;
            if (shifted){ z=(zs+1)&31; h=(hs+4)&31; w=(ws+4)&31; }
            else        { z=zs; h=hs; w=ws; }
            src = ((b*32+z)*32+h)*32+w;
        } else {
            src = r;
        }
        const float* row = in + (size_t)src*CCH;
        float v0 = row[lane], v1 = row[lane+64], v2 = row[lane+128];
        float s = v0+v1+v2, q = v0*v0+v1*v1+v2*v2;
        #pragma unroll
        for (int o=1;o<64;o<<=1){ s += __shfl_xor(s,o); q += __shfl_xor(q,o); }
        float mean = s*(1.f/192.f);
        float rstd = rsqrtf(q*(1.f/192.f) - mean*mean + 1e-5f);
        unsigned short* op = outp + (size_t)lr*CCH;
        op[lane    ] = f2bf((v0-mean)*rstd*g0 + c0);
        op[lane+64 ] = f2bf((v1-mean)*rstd*gA + cA);
        op[lane+128] = f2bf((v2-mean)*rstd*gB + cB);
    }
}

// ---------------- bf16 MFMA GEMM (NT = n-tiles of 16 per block) -----------
// XCD swizzle: bijective remap (nwg % 8 == 0 for all our grids).
// R23: double-buffered K-loop (issue-early/wait-late, 1 barrier/k-step,
// loads overlap MFMA; R11-proven machinery, now on 24-40KB LDS kernels).
// MODE 2: window-reverse residual add (fp32 e).
// MODE 5: qkv split: n<384 -> Ch[m][384] (Q|K); n>=384 -> Vout[win][d][tok].
// MODE 6: fc1: gelu(v) -> bf16 h[m][768].
// MODE 7: fc2: e[(m+row0)][n] += v (plain rows, no window mapping).
template<int MODE, int NT>
__global__ __launch_bounds__(256) void gemm_mfma(
    const unsigned short* __restrict__ A, const unsigned short* __restrict__ Bt,
    const float* __restrict__ bias, void* __restrict__ Cout,
    unsigned short* __restrict__ Vout,
    int N, int K, int shifted, int row0)
{
    __shared__ __align__(16) unsigned short As[2][128*32];
    __shared__ __align__(16) unsigned short Bs[2][NT*16*32];
    int t = threadIdx.x;
    int wave = t >> 6, lane = t & 63;
    int quad = lane >> 4, l16 = lane & 15;

    // ---- XCD-aware bijective swizzle (nwg % 8 == 0 guaranteed) ----
    int nwg = gridDim.x * gridDim.y;
    int lin = blockIdx.y * gridDim.x + blockIdx.x;
    int wg  = (lin & 7) * (nwg >> 3) + (lin >> 3);
    int bx  = wg % gridDim.x, by = wg / gridDim.x;
    int m0 = by * 128, n0 = bx * (NT*16);

    f32x4 acc[2][NT] = {};
    int ldrow = lane >> 2;
    int ldk   = (lane & 3) * 8;

    auto stage = [&](int ki, int b){
        int k0 = ki * 32;
        #pragma unroll
        for (int s2 = 0; s2 < 2; ++s2){
            int s = wave*2 + s2;
            async16(A + (size_t)(m0 + s*16 + ldrow)*K + k0 + ldk, &As[b][s*512]);
        }
        #pragma unroll
        for (int i = 0; i < NT/4; ++i){
            async16(Bt + (size_t)(n0 + i*64 + wave*16 + ldrow)*K + k0 + ldk,
                    &Bs[b][i*2048 + wave*512]);
        }
    };

    int nk = K >> 5;
    // prologue: stage k-step 0 into buf 0, full drain
    stage(0, 0);
    asm volatile("s_waitcnt vmcnt(0)" ::: "memory");
    __builtin_amdgcn_s_barrier();
    __builtin_amdgcn_sched_barrier(0);

    for (int ki = 0; ki < nk; ++ki){
        int cur = ki & 1;
        if (ki + 1 < nk) stage(ki + 1, cur ^ 1);   // issue next BEFORE compute
        bf16x8 af[2], bfr[NT];
        #pragma unroll
        for (int mt=0; mt<2; ++mt)
            af[mt] = *(const bf16x8*)&As[cur][(wave*32 + mt*16 + l16)*32 + quad*8];
        #pragma unroll
        for (int nt=0; nt<NT; ++nt)
            bfr[nt] = *(const bf16x8*)&Bs[cur][(nt*16 + l16)*32 + quad*8];
        #pragma unroll
        for (int mt=0; mt<2; ++mt)
            #pragma unroll
            for (int nt=0; nt<NT; ++nt)
                acc[mt][nt] = __builtin_amdgcn_mfma_f32_16x16x32_bf16(
                    af[mt], bfr[nt], acc[mt][nt], 0, 0, 0);
        asm volatile("s_waitcnt vmcnt(0)" ::: "memory");   // my next-buf loads landed
        __builtin_amdgcn_s_barrier();                       // all waves done reading cur
        __builtin_amdgcn_sched_barrier(0);
    }

    float* Cf = (float*)Cout;
    unsigned short* Ch = (unsigned short*)Cout;
    #pragma unroll
    for (int mt=0; mt<2; ++mt){
        #pragma unroll
        for (int nt=0; nt<NT; ++nt){
            int n = n0 + nt*16 + l16;
            if (MODE==5 && n0 + nt*16 >= 384){
                int d = n - 384;
                int win = m0 >> 7;
                int tok0 = wave*32 + mt*16 + quad*4;
                float bn = bias[n];
                ushort4 vv;
                vv.x = f2bf(acc[mt][nt][0]+bn); vv.y = f2bf(acc[mt][nt][1]+bn);
                vv.z = f2bf(acc[mt][nt][2]+bn); vv.w = f2bf(acc[mt][nt][3]+bn);
                *(ushort4*)&Vout[((size_t)win*192 + d)*128 + tok0] = vv;
                continue;
            }
            #pragma unroll
            for (int r=0; r<4; ++r){
                int m = m0 + wave*32 + mt*16 + quad*4 + r;
                float v = acc[mt][nt][r] + bias[n];
                if (MODE==5){
                    Ch[(size_t)m*384 + n] = f2bf(v);
                } else if (MODE==6){
                    Ch[(size_t)m*768 + n] = f2bf(gelu_f(v));
                } else if (MODE==7){
                    Cf[(size_t)(m + row0)*CCH + n] += v;
                } else {
                    int mg = m + row0;
                    int wb = mg>>7, tok = mg&127;
                    int b = wb>>8, nw = wb&255;
                    int zs = (nw>>4)*2 + (tok>>6);
                    int hs = ((nw>>2)&3)*8 + ((tok>>3)&7);
                    int ws = (nw&3)*8 + (tok&7);
                    int z,h,w;
                    if (shifted){ z=(zs+1)&31; h=(hs+4)&31; w=(ws+4)&31; }
                    else        { z=zs; h=hs; w=ws; }
                    Cf[(size_t)(((b*32+z)*32+h)*32+w)*CCH + n] += v;
                }
            }
        }
    }
}

// ---------------- MFMA attention ------------------------------------------
// K/V time-share one 8KB LDS buffer. Bias (pre-scaled 1/scale) preloaded
// from Ps into sacc as the MFMA C-initializer, shifted-window mask folded
// into the preload (-100/scale where groups differ).
__global__ __launch_bounds__(256) void attn_mfma(
    const unsigned short* __restrict__ qk,
    const unsigned short* __restrict__ vbuf,
    unsigned short* __restrict__ obuf,
    const unsigned short* __restrict__ bias_layer,
    int shifted, int wb0)
{
    __shared__ __align__(16) unsigned short KV[4096];
    __shared__ __align__(16) unsigned short Ps[16384];
    __shared__ float linv[128];
    __shared__ int grp[128];

    int t = threadIdx.x;
    int wave = t >> 6, lane = t & 63;
    int quad = lane >> 4, l16 = lane & 15;
    int wb = blockIdx.x / HEADS;
    int head = blockIdx.x % HEADS;
    int nw = (wb + wb0) & 255;

    const unsigned short* qkw = qk + (size_t)wb*128*384;

    bf16x8 af[2];
    #pragma unroll
    for (int mt=0; mt<2; ++mt)
        af[mt] = *(const bf16x8*)(qkw + (size_t)(wave*32 + mt*16 + l16)*384 + head*32 + quad*8);

    int chunk = lane >> 4, low = lane & 15;
    {
        #pragma unroll
        for (int i=0; i<2; ++i){
            int j = wave*2 + i;
            async16(qkw + (size_t)(j*16 + low)*384 + 192 + head*32 + chunk*8, &KV[j*512]);
        }
        const unsigned short* bsrc = bias_layer + (size_t)head*16384;
        #pragma unroll
        for (int i=0; i<8; ++i){
            int j = wave*8 + i;
            async16(bsrc + j*512 + lane*8, &Ps[j*512]);
        }
    }
    if (t < 128 && shifted){
        int zs = (nw>>4)*2 + (t>>6);
        int hs = ((nw>>2)&3)*8 + ((t>>3)&7);
        int ws = (nw&3)*8 + (t&7);
        grp[t] = zone_z(zs)*9 + zone_hw(hs)*3 + zone_hw(ws);
    }
    __syncthreads();

    // ---- preload pre-scaled bias (+ folded shift mask) into accumulator ----
    const float mask_ps = -565.6854249492380f;   // -100 / scale
    f32x4 sacc[2][8];
    #pragma unroll
    for (int mt=0; mt<2; ++mt){
        #pragma unroll
        for (int r=0; r<4; ++r){
            int row = wave*32 + mt*16 + quad*4 + r;
            int myg = shifted ? grp[row] : 0;
            int rbase = (wave*2+mt)*2048 + (quad*4+r)*8;
            #pragma unroll
            for (int nt=0; nt<8; ++nt){
                int off = rbase + (nt>>1)*512 + (((nt&1)<<1) + (l16>>3))*128 + (l16&7);
                float b = bf2f(Ps[off]);
                if (shifted && grp[nt*16+l16] != myg) b += mask_ps;
                sacc[mt][nt][r] = b;
            }
        }
    }

    #pragma unroll
    for (int nt=0; nt<8; ++nt){
        bf16x8 bfr = *(const bf16x8*)&KV[nt*512 + quad*128 + l16*8];
        sacc[0][nt] = __builtin_amdgcn_mfma_f32_16x16x32_bf16(af[0], bfr, sacc[0][nt], 0,0,0);
        sacc[1][nt] = __builtin_amdgcn_mfma_f32_16x16x32_bf16(af[1], bfr, sacc[1][nt], 0,0,0);
    }

    // all waves done reading K from KV -> safe to overwrite with V
    __syncthreads();
    {
        const unsigned short* vb = vbuf + ((size_t)wb*192 + head*32)*128;
        #pragma unroll
        for (int i=0; i<2; ++i){
            int j = wave*2 + i; int dgrp = j>>2, tg = j&3;
            async16(vb + (size_t)(dgrp*16 + low)*128 + tg*32 + chunk*8, &KV[j*512]);
        }
    }

    const float scale = 0.17677669529663689f;
    #pragma unroll
    for (int mt=0; mt<2; ++mt){
        #pragma unroll
        for (int r=0; r<4; ++r){
            int row = wave*32 + mt*16 + quad*4 + r;
            int rbase = (wave*2+mt)*2048 + (quad*4+r)*8;
            float sv[8]; int offv[8];
            float mloc = -1e30f;
            #pragma unroll
            for (int nt=0; nt<8; ++nt){
                int off = rbase + (nt>>1)*512 + (((nt&1)<<1) + (l16>>3))*128 + (l16&7);
                offv[nt] = off;
                float s = sacc[mt][nt][r]*scale;
                sv[nt] = s;
                mloc = fmaxf(mloc, s);
            }
            #pragma unroll
            for (int off=1; off<16; off<<=1) mloc = fmaxf(mloc, __shfl_xor(mloc, off));
            float lloc = 0.f;
            #pragma unroll
            for (int nt=0; nt<8; ++nt){
                float p = __expf(sv[nt]-mloc);
                sv[nt] = p; lloc += p;
            }
            #pragma unroll
            for (int off=1; off<16; off<<=1) lloc += __shfl_xor(lloc, off);
            #pragma unroll
            for (int nt=0; nt<8; ++nt)
                Ps[offv[nt]] = f2bf(sv[nt]);
            if (l16==0) linv[row] = 1.f/lloc;
        }
    }
    // V staged + P written; barrier drains V loads
    __syncthreads();

    f32x4 oacc[2][2] = {};
    #pragma unroll
    for (int ks=0; ks<4; ++ks){
        bf16x8 av0 = *(const bf16x8*)&KV[         ks*512 + quad*128 + l16*8];
        bf16x8 av1 = *(const bf16x8*)&KV[ 2048 +  ks*512 + quad*128 + l16*8];
        bf16x8 pf0 = *(const bf16x8*)&Ps[(wave*2+0)*2048 + ks*512 + quad*128 + l16*8];
        bf16x8 pf1 = *(const bf16x8*)&Ps[(wave*2+1)*2048 + ks*512 + quad*128 + l16*8];
        oacc[0][0] = __builtin_amdgcn_mfma_f32_16x16x32_bf16(av0, pf0, oacc[0][0], 0,0,0);
        oacc[0][1] = __builtin_amdgcn_mfma_f32_16x16x32_bf16(av1, pf0, oacc[0][1], 0,0,0);
        oacc[1][0] = __builtin_amdgcn_mfma_f32_16x16x32_bf16(av0, pf1, oacc[1][0], 0,0,0);
        oacc[1][1] = __builtin_amdgcn_mfma_f32_16x16x32_bf16(av1, pf1, oacc[1][1], 0,0,0);
    }

    #pragma unroll
    for (int mt=0; mt<2; ++mt){
        int token = wave*32 + mt*16 + l16;
        float inv = linv[token];
        unsigned short* dst = obuf + (size_t)(wb*128+token)*CCH + head*32;
        #pragma unroll
        for (int dt=0; dt<2; ++dt){
            ushort4 v4;
            v4.x = f2bf(oacc[mt][dt][0]*inv);
            v4.y = f2bf(oacc[mt][dt][1]*inv);
            v4.z = f2bf(oacc[mt][dt][2]*inv);
            v4.w = f2bf(oacc[mt][dt][3]*inv);
            *(ushort4*)&dst[dt*16 + quad*4] = v4;
        }
    }
}

extern "C" void kernel_launch(void* const* d_in, const int* in_sizes, int n_in,
                              void* d_out, int out_size, void* d_ws, size_t ws_size,
                              hipStream_t stream) {
    const float* x       = (const float*)d_in[0];
    const float* pe_w    = (const float*)d_in[1];
    const float* pe_b    = (const float*)d_in[2];
    const float* pe_ln_g = (const float*)d_in[3];
    const float* pe_ln_b = (const float*)d_in[4];
    const float* ln1_g   = (const float*)d_in[5];
    const float* ln1_b   = (const float*)d_in[6];
    const float* qkv_w   = (const float*)d_in[7];
    const float* qkv_b   = (const float*)d_in[8];
    const float* proj_w  = (const float*)d_in[9];
    const float* proj_b  = (const float*)d_in[10];
    const float* rpb     = (const float*)d_in[11];
    const float* ln2_g   = (const float*)d_in[12];
    const float* ln2_b   = (const float*)d_in[13];
    const float* fc1_w   = (const float*)d_in[14];
    const float* fc1_b   = (const float*)d_in[15];
    const float* fc2_w   = (const float*)d_in[16];
    const float* fc2_b   = (const float*)d_in[17];
    const float* rec_w   = (const float*)d_in[18];
    const float* rec_b   = (const float*)d_in[19];
    float* out = (float*)d_out;
    char* wsb = (char*)d_ws;

    float*          e        = (float*)wsb;
    unsigned short* bias_il  = (unsigned short*)(wsb + 50331648);
    unsigned short* wt       = (unsigned short*)(wsb + 51904512);
    unsigned short* pwb      = wt + 1769472;
    unsigned short* rwt      = wt + 1794048;
    char*           stage    = wsb + 55541760;
    size_t scap = ws_size > 55541760 ? ws_size - 55541760 : 0;

    int WCH = 512;
    while (WCH > 16 && (size_t)WCH*128*1920 > scap) WCH >>= 1;

    for (int d = 0; d < 4; ++d){
        unsigned short* wl = wt + (size_t)d*442368;
        wt_convert<<<(110592+255)/256, 256, 0, stream>>>(qkv_w  + (size_t)d*110592, wl,          192, 576);
        wt_convert<<<( 36864+255)/256, 256, 0, stream>>>(proj_w + (size_t)d* 36864, wl + 110592, 192, 192);
        wt_convert<<<(147456+255)/256, 256, 0, stream>>>(fc1_w  + (size_t)d*147456, wl + 147456, 192, 768);
        wt_convert<<<(147456+255)/256, 256, 0, stream>>>(fc2_w  + (size_t)d*147456, wl + 294912, 768, 192);
    }
    pe_conv<<<96, 256, 0, stream>>>(pe_w, pwb, 24576);
    wt_convert<<<96, 256, 0, stream>>>(rec_w, rwt, 192, 128);

    bias_precompute<<<24, 128, 0, stream>>>(rpb, bias_il);
    patch_embed_mfma<<<1024, 256, 0, stream>>>(x, pwb, pe_b, pe_ln_g, pe_ln_b, e);

    for (int d = 0; d < 4; ++d){
        int sh = d & 1;
        unsigned short* wl = wt + (size_t)d*442368;
        for (int w0 = 0; w0 < 512; w0 += WCH){
            int rows = WCH*128;
            unsigned short* bufc = (unsigned short*)stage;
            unsigned short* qkc  = (unsigned short*)(stage + (size_t)rows*384);
            unsigned short* vc   = (unsigned short*)(stage + (size_t)rows*1152);
            unsigned short* oc   = (unsigned short*)(stage + (size_t)rows*1536);
            ln_kernel<<<rows/8, 256, 0, stream>>>(
                e, bufc, ln1_g + d*CCH, ln1_b + d*CCH, sh, w0*128, 1);
            gemm_mfma<5,4><<<dim3(9, rows/128), 256, 0, stream>>>(
                bufc, wl, qkv_b + d*3*CCH, qkc, vc, 576, 192, 0, 0);
            attn_mfma<<<WCH*HEADS, 256, 0, stream>>>(
                qkc, vc, oc, bias_il + (size_t)d*HEADS*16384, sh, w0);
            gemm_mfma<2,4><<<dim3(3, rows/128), 256, 0, stream>>>(
                oc, wl + 110592, proj_b + d*CCH, e, nullptr, 192, 192, sh, w0*128);
        }
        // ---- MLP: ln2 -> fc1+gelu(h bf16, NT=8) -> fc2+residual (NT=12) ----
        for (int r0 = 0; r0 < 65536; r0 += WCH*128){
            int rows = WCH*128;
            unsigned short* abuf = (unsigned short*)stage;
            unsigned short* hbuf = (unsigned short*)(stage + (size_t)rows*384);
            ln_kernel<<<rows/8, 256, 0, stream>>>(
                e, abuf, ln2_g + d*CCH, ln2_b + d*CCH, 0, r0, 0);
            gemm_mfma<6,8><<<dim3(6, rows/128), 256, 0, stream>>>(
                abuf, wl + 147456, fc1_b + d*4*CCH, hbuf, nullptr, 768, 192, 0, 0);
            gemm_mfma<7,12><<<dim3(1, rows/128), 256, 0, stream>>>(
                hbuf, wl + 294912, fc2_b + d*CCH, e, nullptr, 192, 768, 0, r0);
        }
    }
    recon_mfma<<<1024, 256, 0, stream>>>(e, rwt, rec_b, out);
}

// Round 17
// 1128.160 us; speedup vs baseline: 1.0145x; 1.0145x over previous
//
#include <hip/hip_runtime.h>
#include <math.h>

// SwinDecoder on MI355X. Round 24: revert R23's gemm dbuf (+13us regression;
// 6th neutral/negative source-level pipelining result - compiler TLP already
// captures the overlap, LDS doubling taxes residency). This is byte-for-byte
// the R22 kernel: the verified best at 1131.3us.
// Win ledger: MLP split + NT widening (-94), XCD swizzle (-96), wave-per-row
// LN (-142), attn mask fold into preload (-11.5). 1449 -> 1131 us (-22%).
// ws layout (bytes):
//   e        : 0          .. 50,331,648   fp32 [65536][192]
//   bias_il  : 50,331,648 .. 51,118,080   bf16 interleaved [4][6][16384] (pre-scaled)
//   wt       : 51,904,512 .. 55,541,760   bf16 weights (4 layers + pe + rec)
//   stage    : 55,541,760 .. attn: bufc|qkc|vc|oc ; mlp: a(384B/row)|h(1536B/row)

#define CCH 192
#define HEADS 6

typedef __attribute__((ext_vector_type(8))) short bf16x8;
typedef __attribute__((ext_vector_type(4))) float f32x4;

__device__ __forceinline__ unsigned short f2bf(float f){
    union { float f; unsigned int u; } x; x.f = f;
    unsigned int r = (x.u + 0x7fffu + ((x.u >> 16) & 1u)) >> 16;
    return (unsigned short)r;
}
__device__ __forceinline__ float bf2f(unsigned short h){
    union { unsigned int u; float f; } x; x.u = ((unsigned int)h)<<16;
    return x.f;
}

__device__ __forceinline__ void async16(const void* g, void* l){
    __builtin_amdgcn_global_load_lds(
        (const __attribute__((address_space(1))) void*)g,
        (__attribute__((address_space(3))) void*)l, 16, 0, 0);
}

__device__ __forceinline__ ushort4 cvt4(float4 v){
    ushort4 r; r.x=f2bf(v.x); r.y=f2bf(v.y); r.z=f2bf(v.z); r.w=f2bf(v.w);
    return r;
}

__device__ __forceinline__ int zone_z(int z){ return z<30?0:(z<31?1:2); }
__device__ __forceinline__ int zone_hw(int h){ return h<24?0:(h<28?1:2); }

// gelu with A&S 7.1.26 erf: |err| <= 1.5e-7, branchless, 1 v_exp + 1 v_rcp.
__device__ __forceinline__ float gelu_f(float v){
    float xx = v*0.70710678118654752f;
    float ax = fabsf(xx);
    float ti = __builtin_amdgcn_rcpf(fmaf(0.3275911f, ax, 1.f));
    float p  = fmaf(ti, 1.061405429f, -1.453152027f);
    p = fmaf(ti, p, 1.421413741f);
    p = fmaf(ti, p, -0.284496736f);
    p = fmaf(ti, p, 0.254829592f);
    p = p * ti;
    float ex = __expf(-ax*ax);
    float er = fmaf(-p, ex, 1.f);
    er = __builtin_copysignf(er, xx);
    return 0.5f*v*(1.f + er);
}

// ---------------- weight convert+transpose: w[K][N] fp32 -> wt[N][K] bf16 --
__global__ void wt_convert(const float* __restrict__ w, unsigned short* __restrict__ wt,
                           int K, int N)
{
    int idx = blockIdx.x*256 + threadIdx.x;
    if (idx >= K*N) return;
    int n = idx / K, k = idx - n*K;
    wt[idx] = f2bf(w[(size_t)k*N + n]);
}

// ---------------- plain fp32 -> bf16 convert -------------------------------
__global__ void pe_conv(const float* __restrict__ w, unsigned short* __restrict__ o, int n)
{
    int i = blockIdx.x*256 + threadIdx.x;
    if (i < n) o[i] = f2bf(w[i]);
}

// ---- rel-pos bias -> bf16 in MFMA-interleaved layout, PRE-SCALED by ------
// 1/attn_scale so it can be the MFMA C-initializer (s = acc*scale).
__global__ void bias_precompute(const float* __restrict__ rpb,
                                unsigned short* __restrict__ bias_il)
{
    const float inv_scale = 5.656854249492380f;
    int d = blockIdx.x / HEADS, head = blockIdx.x % HEADS;
    int n = threadIdx.x;
    int i1 = n>>6, j1 = (n>>3)&7, k1 = n&7;
    const float* rp = rpb + d*675*HEADS;
    unsigned short* out = bias_il + (size_t)blockIdx.x*16384;
    int rbase = (n>>4)*2048 + (n&15)*8;
    for (int m = 0; m < 128; ++m){
        int i2 = m>>6, j2 = (m>>3)&7, k2 = m&7;
        int idx = (i1-i2+1)*225 + (j1-j2+7)*15 + (k1-k2+7);
        int off = rbase + (m>>5)*512 + ((m>>3)&3)*128 + (m&7);
        out[off] = f2bf(rp[idx*HEADS + head] * inv_scale);
    }
}

// ---------------- patch embed via MFMA, LN fused in epilogue ---------------
__global__ __launch_bounds__(256) void patch_embed_mfma(
    const float* __restrict__ x, const unsigned short* __restrict__ pwb,
    const float* __restrict__ pe_b, const float* __restrict__ gg,
    const float* __restrict__ bb, float* __restrict__ e)
{
    __shared__ __align__(16) unsigned short As[64*132];
    __shared__ __align__(16) unsigned short Bs[96*132];
    int t = threadIdx.x;
    int wave = t>>6, lane = t&63, quad = lane>>4, l16 = lane&15;
    int m0 = blockIdx.x*64;

    {
        int row = t & 63, cg = (t>>6)*8;
        int pos = m0 + row;
        int w = pos&31, h=(pos>>5)&31, z=(pos>>10)&31, b=pos>>15;
        #pragma unroll
        for (int cc=0; cc<8; ++cc){
            int chunk = cg + cc;
            int c = chunk>>3, i=(chunk>>2)&1, j=chunk&3;
            float4 v = *(const float4*)&x[ (((size_t)(b*4+c)*64 + (z*2+i))*128 + (h*4+j))*128 + w*4 ];
            *(ushort4*)&As[row*132 + chunk*4] = cvt4(v);
        }
    }

    f32x4 acc[12] = {};
    #pragma unroll
    for (int ph = 0; ph < 2; ++ph){
        if (ph) __syncthreads();
        #pragma unroll
        for (int it=0; it<6; ++it){
            int g = it*256 + t;
            int row = g >> 4, c8 = g & 15;
            const unsigned short* src = pwb + ((size_t)(ph*96+row))*128 + c8*8;
            uint4 u = *(const uint4*)src;
            unsigned short* dst = &Bs[row*132 + c8*8];
            *(uint2*)dst       = make_uint2(u.x, u.y);
            *(uint2*)(dst+4)   = make_uint2(u.z, u.w);
        }
        __syncthreads();
        #pragma unroll
        for (int ks=0; ks<4; ++ks){
            bf16x8 af = *(const bf16x8*)&As[(wave*16 + l16)*132 + ks*32 + quad*8];
            #pragma unroll
            for (int nt=0; nt<6; ++nt){
                bf16x8 bf = *(const bf16x8*)&Bs[(nt*16 + l16)*132 + ks*32 + quad*8];
                acc[ph*6+nt] = __builtin_amdgcn_mfma_f32_16x16x32_bf16(
                    af, bf, acc[ph*6+nt], 0, 0, 0);
            }
        }
    }

    float pb[12], gv[12], bv[12];
    #pragma unroll
    for (int nt=0; nt<12; ++nt){
        int col = nt*16 + l16;
        pb[nt] = pe_b[col]; gv[nt] = gg[col]; bv[nt] = bb[col];
    }
    #pragma unroll
    for (int r=0; r<4; ++r){
        int row = wave*16 + quad*4 + r;
        int pos = m0 + row;
        float sv[12], s1 = 0.f, s2 = 0.f;
        #pragma unroll
        for (int nt=0; nt<12; ++nt){
            float v = acc[nt][r] + pb[nt];
            sv[nt] = v; s1 += v; s2 += v*v;
        }
        #pragma unroll
        for (int off=1; off<16; off<<=1){
            s1 += __shfl_xor(s1, off); s2 += __shfl_xor(s2, off);
        }
        float mean = s1*(1.f/192.f);
        float rstd = rsqrtf(s2*(1.f/192.f) - mean*mean + 1e-5f);
        #pragma unroll
        for (int nt=0; nt<12; ++nt){
            int col = nt*16 + l16;
            e[(size_t)pos*CCH + col] = (sv[nt]-mean)*rstd*gv[nt] + bv[nt];
        }
    }
}

// ---------------- reconstruction via MFMA ----------------------------------
__global__ __launch_bounds__(256) void recon_mfma(
    const float* __restrict__ e, const unsigned short* __restrict__ rwt,
    const float* __restrict__ rec_b, float* __restrict__ out)
{
    __shared__ __align__(16) unsigned short As[64*196];
    __shared__ __align__(16) unsigned short Bs[64*196];
    int t = threadIdx.x;
    int wave = t>>6, lane = t&63, quad = lane>>4, l16 = lane&15;
    int m0 = blockIdx.x*64;

    #pragma unroll
    for (int it=0; it<12; ++it){
        int g = it*256 + t;
        int row = g/48, c4 = g - row*48;
        float4 v = *(const float4*)&e[(size_t)(m0+row)*CCH + c4*4];
        *(ushort4*)&As[row*196 + c4*4] = cvt4(v);
    }

    f32x4 acc[8] = {};
    #pragma unroll
    for (int ph = 0; ph < 2; ++ph){
        if (ph) __syncthreads();
        #pragma unroll
        for (int it=0; it<6; ++it){
            int g = it*256 + t;
            int row = g/24, c8 = g - row*24;
            const unsigned short* src = rwt + ((size_t)(ph*64+row))*192 + c8*8;
            uint4 u = *(const uint4*)src;
            unsigned short* dst = &Bs[row*196 + c8*8];
            *(uint2*)dst     = make_uint2(u.x, u.y);
            *(uint2*)(dst+4) = make_uint2(u.z, u.w);
        }
        __syncthreads();
        #pragma unroll
        for (int ks=0; ks<6; ++ks){
            bf16x8 af = *(const bf16x8*)&As[(wave*16 + l16)*196 + ks*32 + quad*8];
            #pragma unroll
            for (int nt=0; nt<4; ++nt){
                bf16x8 bf = *(const bf16x8*)&Bs[(nt*16 + l16)*196 + ks*32 + quad*8];
                acc[ph*4+nt] = __builtin_amdgcn_mfma_f32_16x16x32_bf16(
                    af, bf, acc[ph*4+nt], 0, 0, 0);
            }
        }
    }

    #pragma unroll
    for (int nt=0; nt<8; ++nt){
        int col = nt*16 + l16;
        int o = col>>5, i = (col>>4)&1, j = (col>>2)&3, k = col&3;
        float rb = rec_b[o];
        #pragma unroll
        for (int r=0; r<4; ++r){
            int pos = m0 + wave*16 + quad*4 + r;
            int w = pos&31, h=(pos>>5)&31, z=(pos>>10)&31, b=pos>>15;
            out[ (((size_t)(b*4+o)*64 + (z*2+i))*128 + (h*4+j))*128 + (w*4+k) ]
                = acc[nt][r] + rb;
        }
    }
}

// ------- LayerNorm -> bf16 (wave-per-row, 4 waves x 2 rows/block) ----------
// gather=1: window gather (ln1); 0: plain (ln2). Pure 64-lane butterfly,
// no LDS, no barrier. Grid = rows/8.
__global__ __launch_bounds__(256) void ln_kernel(
    const float* __restrict__ in, unsigned short* __restrict__ outp,
    const float* __restrict__ gg, const float* __restrict__ bb,
    int shifted, int row0, int gather)
{
    int lane = threadIdx.x & 63, wave = threadIdx.x >> 6;
    float g0 = gg[lane],  gA = gg[lane+64],  gB = gg[lane+128];
    float c0 = bb[lane],  cA = bb[lane+64],  cB = bb[lane+128];
    #pragma unroll
    for (int rr = 0; rr < 2; ++rr){
        int lr = blockIdx.x*8 + wave*2 + rr;   // chunk-local row
        int r  = lr + row0;                    // global gathered-row index
        int src;
        if (gather){
            int wb = r>>7, tok = r&127;
            int b = wb>>8, nw = wb&255;
            int zs = (nw>>4)*2 + (tok>>6);
            int hs = ((nw>>2)&3)*8 + ((tok>>3)&7);
            int ws = (nw&3)*8 + (tok&7);
            int z,h,w;
            if (shifted){ z=(zs+1)&31; h=(hs+4)&31; w=(ws+4)&31; }
            else        { z=zs; h=hs; w=ws; }
            src = ((b*32+z)*32+h)*32+w;
        } else {
            src = r;
        }
        const float* row = in + (size_t)src*CCH;
        float v0 = row[lane], v1 = row[lane+64], v2 = row[lane+128];
        float s = v0+v1+v2, q = v0*v0+v1*v1+v2*v2;
        #pragma unroll
        for (int o=1;o<64;o<<=1){ s += __shfl_xor(s,o); q += __shfl_xor(q,o); }
        float mean = s*(1.f/192.f);
        float rstd = rsqrtf(q*(1.f/192.f) - mean*mean + 1e-5f);
        unsigned short* op = outp + (size_t)lr*CCH;
        op[lane    ] = f2bf((v0-mean)*rstd*g0 + c0);
        op[lane+64 ] = f2bf((v1-mean)*rstd*gA + cA);
        op[lane+128] = f2bf((v2-mean)*rstd*gB + cB);
    }
}

// ---------------- bf16 MFMA GEMM (NT = n-tiles of 16 per block) -----------
// XCD swizzle: bijective remap (nwg % 8 == 0 for all our grids).
// MODE 2: window-reverse residual add (fp32 e).
// MODE 5: qkv split: n<384 -> Ch[m][384] (Q|K); n>=384 -> Vout[win][d][tok].
// MODE 6: fc1: gelu(v) -> bf16 h[m][768].
// MODE 7: fc2: e[(m+row0)][n] += v (plain rows, no window mapping).
template<int MODE, int NT>
__global__ __launch_bounds__(256) void gemm_mfma(
    const unsigned short* __restrict__ A, const unsigned short* __restrict__ Bt,
    const float* __restrict__ bias, void* __restrict__ Cout,
    unsigned short* __restrict__ Vout,
    int N, int K, int shifted, int row0)
{
    __shared__ __align__(16) unsigned short As[128*32];
    __shared__ __align__(16) unsigned short Bs[NT*16*32];
    int t = threadIdx.x;
    int wave = t >> 6, lane = t & 63;
    int quad = lane >> 4, l16 = lane & 15;

    // ---- XCD-aware bijective swizzle (nwg % 8 == 0 guaranteed) ----
    int nwg = gridDim.x * gridDim.y;
    int lin = blockIdx.y * gridDim.x + blockIdx.x;
    int wg  = (lin & 7) * (nwg >> 3) + (lin >> 3);
    int bx  = wg % gridDim.x, by = wg / gridDim.x;
    int m0 = by * 128, n0 = bx * (NT*16);

    f32x4 acc[2][NT] = {};
    int ldrow = lane >> 2;
    int ldk   = (lane & 3) * 8;

    for (int k0 = 0; k0 < K; k0 += 32){
        #pragma unroll
        for (int s2 = 0; s2 < 2; ++s2){
            int s = wave*2 + s2;
            async16(A + (size_t)(m0 + s*16 + ldrow)*K + k0 + ldk, &As[s*512]);
        }
        #pragma unroll
        for (int i = 0; i < NT/4; ++i){
            async16(Bt + (size_t)(n0 + i*64 + wave*16 + ldrow)*K + k0 + ldk,
                    &Bs[i*2048 + wave*512]);
        }
        __syncthreads();
        bf16x8 af[2], bfr[NT];
        #pragma unroll
        for (int mt=0; mt<2; ++mt)
            af[mt] = *(const bf16x8*)&As[(wave*32 + mt*16 + l16)*32 + quad*8];
        #pragma unroll
        for (int nt=0; nt<NT; ++nt)
            bfr[nt] = *(const bf16x8*)&Bs[(nt*16 + l16)*32 + quad*8];
        #pragma unroll
        for (int mt=0; mt<2; ++mt)
            #pragma unroll
            for (int nt=0; nt<NT; ++nt)
                acc[mt][nt] = __builtin_amdgcn_mfma_f32_16x16x32_bf16(
                    af[mt], bfr[nt], acc[mt][nt], 0, 0, 0);
        __syncthreads();
    }

    float* Cf = (float*)Cout;
    unsigned short* Ch = (unsigned short*)Cout;
    #pragma unroll
    for (int mt=0; mt<2; ++mt){
        #pragma unroll
        for (int nt=0; nt<NT; ++nt){
            int n = n0 + nt*16 + l16;
            if (MODE==5 && n0 + nt*16 >= 384){
                int d = n - 384;
                int win = m0 >> 7;
                int tok0 = wave*32 + mt*16 + quad*4;
                float bn = bias[n];
                ushort4 vv;
                vv.x = f2bf(acc[mt][nt][0]+bn); vv.y = f2bf(acc[mt][nt][1]+bn);
                vv.z = f2bf(acc[mt][nt][2]+bn); vv.w = f2bf(acc[mt][nt][3]+bn);
                *(ushort4*)&Vout[((size_t)win*192 + d)*128 + tok0] = vv;
                continue;
            }
            #pragma unroll
            for (int r=0; r<4; ++r){
                int m = m0 + wave*32 + mt*16 + quad*4 + r;
                float v = acc[mt][nt][r] + bias[n];
                if (MODE==5){
                    Ch[(size_t)m*384 + n] = f2bf(v);
                } else if (MODE==6){
                    Ch[(size_t)m*768 + n] = f2bf(gelu_f(v));
                } else if (MODE==7){
                    Cf[(size_t)(m + row0)*CCH + n] += v;
                } else {
                    int mg = m + row0;
                    int wb = mg>>7, tok = mg&127;
                    int b = wb>>8, nw = wb&255;
                    int zs = (nw>>4)*2 + (tok>>6);
                    int hs = ((nw>>2)&3)*8 + ((tok>>3)&7);
                    int ws = (nw&3)*8 + (tok&7);
                    int z,h,w;
                    if (shifted){ z=(zs+1)&31; h=(hs+4)&31; w=(ws+4)&31; }
                    else        { z=zs; h=hs; w=ws; }
                    Cf[(size_t)(((b*32+z)*32+h)*32+w)*CCH + n] += v;
                }
            }
        }
    }
}

// ---------------- MFMA attention ------------------------------------------
// K/V time-share one 8KB LDS buffer. Bias (pre-scaled 1/scale) preloaded
// from Ps into sacc as the MFMA C-initializer, shifted-window mask folded
// into the preload (-100/scale where groups differ).
__global__ __launch_bounds__(256) void attn_mfma(
    const unsigned short* __restrict__ qk,
    const unsigned short* __restrict__ vbuf,
    unsigned short* __restrict__ obuf,
    const unsigned short* __restrict__ bias_layer,
    int shifted, int wb0)
{
    __shared__ __align__(16) unsigned short KV[4096];
    __shared__ __align__(16) unsigned short Ps[16384];
    __shared__ float linv[128];
    __shared__ int grp[128];

    int t = threadIdx.x;
    int wave = t >> 6, lane = t & 63;
    int quad = lane >> 4, l16 = lane & 15;
    int wb = blockIdx.x / HEADS;
    int head = blockIdx.x % HEADS;
    int nw = (wb + wb0) & 255;

    const unsigned short* qkw = qk + (size_t)wb*128*384;

    bf16x8 af[2];
    #pragma unroll
    for (int mt=0; mt<2; ++mt)
        af[mt] = *(const bf16x8*)(qkw + (size_t)(wave*32 + mt*16 + l16)*384 + head*32 + quad*8);

    int chunk = lane >> 4, low = lane & 15;
    {
        #pragma unroll
        for (int i=0; i<2; ++i){
            int j = wave*2 + i;
            async16(qkw + (size_t)(j*16 + low)*384 + 192 + head*32 + chunk*8, &KV[j*512]);
        }
        const unsigned short* bsrc = bias_layer + (size_t)head*16384;
        #pragma unroll
        for (int i=0; i<8; ++i){
            int j = wave*8 + i;
            async16(bsrc + j*512 + lane*8, &Ps[j*512]);
        }
    }
    if (t < 128 && shifted){
        int zs = (nw>>4)*2 + (t>>6);
        int hs = ((nw>>2)&3)*8 + ((t>>3)&7);
        int ws = (nw&3)*8 + (t&7);
        grp[t] = zone_z(zs)*9 + zone_hw(hs)*3 + zone_hw(ws);
    }
    __syncthreads();

    // ---- preload pre-scaled bias (+ folded shift mask) into accumulator ----
    const float mask_ps = -565.6854249492380f;   // -100 / scale
    f32x4 sacc[2][8];
    #pragma unroll
    for (int mt=0; mt<2; ++mt){
        #pragma unroll
        for (int r=0; r<4; ++r){
            int row = wave*32 + mt*16 + quad*4 + r;
            int myg = shifted ? grp[row] : 0;
            int rbase = (wave*2+mt)*2048 + (quad*4+r)*8;
            #pragma unroll
            for (int nt=0; nt<8; ++nt){
                int off = rbase + (nt>>1)*512 + (((nt&1)<<1) + (l16>>3))*128 + (l16&7);
                float b = bf2f(Ps[off]);
                if (shifted && grp[nt*16+l16] != myg) b += mask_ps;
                sacc[mt][nt][r] = b;
            }
        }
    }

    #pragma unroll
    for (int nt=0; nt<8; ++nt){
        bf16x8 bfr = *(const bf16x8*)&KV[nt*512 + quad*128 + l16*8];
        sacc[0][nt] = __builtin_amdgcn_mfma_f32_16x16x32_bf16(af[0], bfr, sacc[0][nt], 0,0,0);
        sacc[1][nt] = __builtin_amdgcn_mfma_f32_16x16x32_bf16(af[1], bfr, sacc[1][nt], 0,0,0);
    }

    // all waves done reading K from KV -> safe to overwrite with V
    __syncthreads();
    {
        const unsigned short* vb = vbuf + ((size_t)wb*192 + head*32)*128;
        #pragma unroll
        for (int i=0; i<2; ++i){
            int j = wave*2 + i; int dgrp = j>>2, tg = j&3;
            async16(vb + (size_t)(dgrp*16 + low)*128 + tg*32 + chunk*8, &KV[j*512]);
        }
    }

    const float scale = 0.17677669529663689f;
    #pragma unroll
    for (int mt=0; mt<2; ++mt){
        #pragma unroll
        for (int r=0; r<4; ++r){
            int row = wave*32 + mt*16 + quad*4 + r;
            int rbase = (wave*2+mt)*2048 + (quad*4+r)*8;
            float sv[8]; int offv[8];
            float mloc = -1e30f;
            #pragma unroll
            for (int nt=0; nt<8; ++nt){
                int off = rbase + (nt>>1)*512 + (((nt&1)<<1) + (l16>>3))*128 + (l16&7);
                offv[nt] = off;
                float s = sacc[mt][nt][r]*scale;
                sv[nt] = s;
                mloc = fmaxf(mloc, s);
            }
            #pragma unroll
            for (int off=1; off<16; off<<=1) mloc = fmaxf(mloc, __shfl_xor(mloc, off));
            float lloc = 0.f;
            #pragma unroll
            for (int nt=0; nt<8; ++nt){
                float p = __expf(sv[nt]-mloc);
                sv[nt] = p; lloc += p;
            }
            #pragma unroll
            for (int off=1; off<16; off<<=1) lloc += __shfl_xor(lloc, off);
            #pragma unroll
            for (int nt=0; nt<8; ++nt)
                Ps[offv[nt]] = f2bf(sv[nt]);
            if (l16==0) linv[row] = 1.f/lloc;
        }
    }
    // V staged + P written; barrier drains V loads
    __syncthreads();

    f32x4 oacc[2][2] = {};
    #pragma unroll
    for (int ks=0; ks<4; ++ks){
        bf16x8 av0 = *(const bf16x8*)&KV[         ks*512 + quad*128 + l16*8];
        bf16x8 av1 = *(const bf16x8*)&KV[ 2048 +  ks*512 + quad*128 + l16*8];
        bf16x8 pf0 = *(const bf16x8*)&Ps[(wave*2+0)*2048 + ks*512 + quad*128 + l16*8];
        bf16x8 pf1 = *(const bf16x8*)&Ps[(wave*2+1)*2048 + ks*512 + quad*128 + l16*8];
        oacc[0][0] = __builtin_amdgcn_mfma_f32_16x16x32_bf16(av0, pf0, oacc[0][0], 0,0,0);
        oacc[0][1] = __builtin_amdgcn_mfma_f32_16x16x32_bf16(av1, pf0, oacc[0][1], 0,0,0);
        oacc[1][0] = __builtin_amdgcn_mfma_f32_16x16x32_bf16(av0, pf1, oacc[1][0], 0,0,0);
        oacc[1][1] = __builtin_amdgcn_mfma_f32_16x16x32_bf16(av1, pf1, oacc[1][1], 0,0,0);
    }

    #pragma unroll
    for (int mt=0; mt<2; ++mt){
        int token = wave*32 + mt*16 + l16;
        float inv = linv[token];
        unsigned short* dst = obuf + (size_t)(wb*128+token)*CCH + head*32;
        #pragma unroll
        for (int dt=0; dt<2; ++dt){
            ushort4 v4;
            v4.x = f2bf(oacc[mt][dt][0]*inv);
            v4.y = f2bf(oacc[mt][dt][1]*inv);
            v4.z = f2bf(oacc[mt][dt][2]*inv);
            v4.w = f2bf(oacc[mt][dt][3]*inv);
            *(ushort4*)&dst[dt*16 + quad*4] = v4;
        }
    }
}

extern "C" void kernel_launch(void* const* d_in, const int* in_sizes, int n_in,
                              void* d_out, int out_size, void* d_ws, size_t ws_size,
                              hipStream_t stream) {
    const float* x       = (const float*)d_in[0];
    const float* pe_w    = (const float*)d_in[1];
    const float* pe_b    = (const float*)d_in[2];
    const float* pe_ln_g = (const float*)d_in[3];
    const float* pe_ln_b = (const float*)d_in[4];
    const float* ln1_g   = (const float*)d_in[5];
    const float* ln1_b   = (const float*)d_in[6];
    const float* qkv_w   = (const float*)d_in[7];
    const float* qkv_b   = (const float*)d_in[8];
    const float* proj_w  = (const float*)d_in[9];
    const float* proj_b  = (const float*)d_in[10];
    const float* rpb     = (const float*)d_in[11];
    const float* ln2_g   = (const float*)d_in[12];
    const float* ln2_b   = (const float*)d_in[13];
    const float* fc1_w   = (const float*)d_in[14];
    const float* fc1_b   = (const float*)d_in[15];
    const float* fc2_w   = (const float*)d_in[16];
    const float* fc2_b   = (const float*)d_in[17];
    const float* rec_w   = (const float*)d_in[18];
    const float* rec_b   = (const float*)d_in[19];
    float* out = (float*)d_out;
    char* wsb = (char*)d_ws;

    float*          e        = (float*)wsb;
    unsigned short* bias_il  = (unsigned short*)(wsb + 50331648);
    unsigned short* wt       = (unsigned short*)(wsb + 51904512);
    unsigned short* pwb      = wt + 1769472;
    unsigned short* rwt      = wt + 1794048;
    char*           stage    = wsb + 55541760;
    size_t scap = ws_size > 55541760 ? ws_size - 55541760 : 0;

    int WCH = 512;
    while (WCH > 16 && (size_t)WCH*128*1920 > scap) WCH >>= 1;

    for (int d = 0; d < 4; ++d){
        unsigned short* wl = wt + (size_t)d*442368;
        wt_convert<<<(110592+255)/256, 256, 0, stream>>>(qkv_w  + (size_t)d*110592, wl,          192, 576);
        wt_convert<<<( 36864+255)/256, 256, 0, stream>>>(proj_w + (size_t)d* 36864, wl + 110592, 192, 192);
        wt_convert<<<(147456+255)/256, 256, 0, stream>>>(fc1_w  + (size_t)d*147456, wl + 147456, 192, 768);
        wt_convert<<<(147456+255)/256, 256, 0, stream>>>(fc2_w  + (size_t)d*147456, wl + 294912, 768, 192);
    }
    pe_conv<<<96, 256, 0, stream>>>(pe_w, pwb, 24576);
    wt_convert<<<96, 256, 0, stream>>>(rec_w, rwt, 192, 128);

    bias_precompute<<<24, 128, 0, stream>>>(rpb, bias_il);
    patch_embed_mfma<<<1024, 256, 0, stream>>>(x, pwb, pe_b, pe_ln_g, pe_ln_b, e);

    for (int d = 0; d < 4; ++d){
        int sh = d & 1;
        unsigned short* wl = wt + (size_t)d*442368;
        for (int w0 = 0; w0 < 512; w0 += WCH){
            int rows = WCH*128;
            unsigned short* bufc = (unsigned short*)stage;
            unsigned short* qkc  = (unsigned short*)(stage + (size_t)rows*384);
            unsigned short* vc   = (unsigned short*)(stage + (size_t)rows*1152);
            unsigned short* oc   = (unsigned short*)(stage + (size_t)rows*1536);
            ln_kernel<<<rows/8, 256, 0, stream>>>(
                e, bufc, ln1_g + d*CCH, ln1_b + d*CCH, sh, w0*128, 1);
            gemm_mfma<5,4><<<dim3(9, rows/128), 256, 0, stream>>>(
                bufc, wl, qkv_b + d*3*CCH, qkc, vc, 576, 192, 0, 0);
            attn_mfma<<<WCH*HEADS, 256, 0, stream>>>(
                qkc, vc, oc, bias_il + (size_t)d*HEADS*16384, sh, w0);
            gemm_mfma<2,4><<<dim3(3, rows/128), 256, 0, stream>>>(
                oc, wl + 110592, proj_b + d*CCH, e, nullptr, 192, 192, sh, w0*128);
        }
        // ---- MLP: ln2 -> fc1+gelu(h bf16, NT=8) -> fc2+residual (NT=12) ----
        for (int r0 = 0; r0 < 65536; r0 += WCH*128){
            int rows = WCH*128;
            unsigned short* abuf = (unsigned short*)stage;
            unsigned short* hbuf = (unsigned short*)(stage + (size_t)rows*384);
            ln_kernel<<<rows/8, 256, 0, stream>>>(
                e, abuf, ln2_g + d*CCH, ln2_b + d*CCH, 0, r0, 0);
            gemm_mfma<6,8><<<dim3(6, rows/128), 256, 0, stream>>>(
                abuf, wl + 147456, fc1_b + d*4*CCH, hbuf, nullptr, 768, 192, 0, 0);
            gemm_mfma<7,12><<<dim3(1, rows/128), 256, 0, stream>>>(
                hbuf, wl + 294912, fc2_b + d*CCH, e, nullptr, 192, 768, 0, r0);
        }
    }
    recon_mfma<<<1024, 256, 0, stream>>>(e, rwt, rec_b, out);
}